// Round 17
// baseline (41.959 us; speedup 1.0000x reference)
//
#include <hip/hip_runtime.h>
#include <math.h>

#define NB 8192
#define ND 128
#define NT 64        // number of 128-row tiles
#define NTRI 2080    // NT*(NT+1)/2 upper-triangle tile pairs
#define TPB 4        // tile-pairs per block (pipelined)
#define NTRB (NTRI / TPB)   // 520 triangle blocks
#define NPOSB 128    // per-label blocks (dispatch FIRST: bids 0..127)
#define NLAB 512
#define MAXM 64
#define NRF 64       // k_rowsfinal blocks (128 rows each)

typedef unsigned short u16;
typedef unsigned int u32;
typedef __attribute__((ext_vector_type(8))) short bf16x8;
typedef __attribute__((ext_vector_type(4))) float f32x4;

#define G2 369.3299304675746f         // gamma * log2(e)
#define NEG_C (-23.083120654223414f)  // -G2/16
#define SENT (-1e30f)
#define LN2F 0.6931471805599453f

static __device__ __forceinline__ void gload16(const void* g, void* l) {
  __builtin_amdgcn_global_load_lds(
      (const __attribute__((address_space(1))) u32*)g,
      (__attribute__((address_space(3))) u32*)l, 16, 0, 0);
}

static __device__ __forceinline__ float fexp2(float x) {
  return __builtin_amdgcn_exp2f(x);
}

static __device__ __forceinline__ u16 f2bf(float f) {
  u32 u = __float_as_uint(f);
  u32 r = (u + 0x7FFF + ((u >> 16) & 1)) >> 16;   // RNE
  return (u16)r;
}

static __device__ __forceinline__ float wave_sum_f(float v) {
  #pragma unroll
  for (int off = 1; off < 64; off <<= 1) v += __shfl_xor(v, off);
  return v;
}

static __device__ __forceinline__ int pre_(int t) { return t * NT - (t * (t - 1)) / 2; }
static __device__ __forceinline__ void trimap(int item, int& ti, int& tj) {
  int t = (int)((129.0f - sqrtf(16641.0f - 8.0f * (float)item)) * 0.5f);
  if (t > NT - 1) t = NT - 1;
  if (t < 0) t = 0;
  while (pre_(t + 1) <= item) ++t;
  while (pre_(t) > item) --t;
  ti = t;
  tj = t + (item - pre_(t));
}

// ---- k1: normalize rows + cast to bf16; reset arrival counter -------------
__global__ __launch_bounds__(512) void k_prep(const float* __restrict__ emb,
                                              u16* __restrict__ e,
                                              int* __restrict__ counters) {
  if (blockIdx.x == 0 && threadIdx.x < 2) counters[threadIdx.x] = 0;
  const int l = threadIdx.x & 63;
  const int w = threadIdx.x >> 6;
  const int row = blockIdx.x * 8 + w;
  const float2 v = reinterpret_cast<const float2*>(emb)[(size_t)row * 64 + l];
  float ss = wave_sum_f(v.x * v.x + v.y * v.y);
  const float inv = 1.0f / fmaxf(sqrtf(ss), 1e-12f);
  ushort2 o;
  o.x = f2bf(v.x * inv);
  o.y = f2bf(v.y * inv);
  reinterpret_cast<ushort2*>(e)[(size_t)row * 64 + l] = o;
}

// staging / A-load / compute as macros -> all register indices compile-time
#define LOADA(AF, ROW0)                                                         \
  _Pragma("unroll")                                                             \
  for (int m_ = 0; m_ < 2; ++m_) {                                              \
    _Pragma("unroll")                                                           \
    for (int ks_ = 0; ks_ < 4; ++ks_)                                           \
      AF[m_][ks_] = *(const bf16x8*)(e + (size_t)((ROW0) + w * 32 + m_ * 16 + lr_) * ND + ks_ * 32 + lg * 8); \
  }

#define STAGEB(BUFOFF, COL0, H)                                                 \
  _Pragma("unroll")                                                             \
  for (int i_ = 0; i_ < 4; ++i_) {                                              \
    const int rr_ = w * 16 + i_ * 4 + lg;                                       \
    gload16(e + (size_t)((COL0) + (H) * 64 + rr_) * ND + (lr_ ^ (rr_ & 15)) * 8, \
            S + (BUFOFF) + w * 4096 + i_ * 1024);                               \
  }

#define COMPUTE_HALF(AF, BUFOFF, H, ROW0, DIAG)                                 \
  {                                                                             \
    f32x4 acc[2][4];                                                            \
    _Pragma("unroll") for (int m_ = 0; m_ < 2; ++m_)                            \
      _Pragma("unroll") for (int n_ = 0; n_ < 4; ++n_)                          \
        _Pragma("unroll") for (int q_ = 0; q_ < 4; ++q_) acc[m_][n_][q_] = 0.f; \
    _Pragma("unroll") for (int ks_ = 0; ks_ < 4; ++ks_) {                       \
      const int kslot_ = (ks_ * 4 + lg) ^ lr_;                                  \
      bf16x8 bfr[4];                                                            \
      _Pragma("unroll") for (int n_ = 0; n_ < 4; ++n_)                          \
        bfr[n_] = *(const bf16x8*)(S + (BUFOFF) + (n_ * 16 + lr_) * 256 + kslot_ * 16); \
      _Pragma("unroll") for (int m_ = 0; m_ < 2; ++m_)                          \
        _Pragma("unroll") for (int n_ = 0; n_ < 4; ++n_)                        \
          acc[m_][n_] = __builtin_amdgcn_mfma_f32_16x16x32_bf16(AF[m_][ks_], bfr[n_], acc[m_][n_], 0, 0, 0); \
    }                                                                           \
    _Pragma("unroll") for (int m_ = 0; m_ < 2; ++m_) {                          \
      _Pragma("unroll") for (int n_ = 0; n_ < 4; ++n_) {                        \
        const bool dmn_ = (DIAG) && (w * 32 + m_ * 16 == (H) * 64 + n_ * 16);   \
        float scc_ = 0.f;                                                       \
        _Pragma("unroll") for (int j_ = 0; j_ < 4; ++j_) {                      \
          const float sv_ = acc[m_][n_][j_];                                    \
          float xn_ = fmaf(sv_ * sv_, G2, NEG_C);                               \
          xn_ = (sv_ > -0.25f) ? xn_ : 0.f;                                     \
          if (dmn_) xn_ = (lr_ == lg * 4 + j_) ? SENT : xn_;                    \
          const float ev_ = fexp2(xn_);                                         \
          sn[m_ * 4 + j_] += ev_;                                               \
          scc_ += ev_;                                                          \
        }                                                                       \
        colp[(H) * 4 + n_] += scc_;                                             \
      }                                                                         \
    }                                                                           \
  }

// ---- k2: pos blocks FIRST (bids 0..127) | pipelined triangle tiles --------
__global__ __launch_bounds__(256, 2) void k_mainpos(const u16* __restrict__ e,
                                                    const int* __restrict__ labels,
                                                    float* __restrict__ part,
                                                    float* __restrict__ poscorr) {
  __shared__ __align__(16) char S[34816];   // buf0(16K) buf1(16K) colbuf(2K)
  float* colbuf = (float*)(S + 32768);
  const int bid = blockIdx.x;
  const int tid = threadIdx.x;
  const int l = tid & 63;
  const int w = tid >> 6;
  const int lr_ = l & 15;
  const int lg = l >> 4;

  if (bid >= NPOSB) {
    // ============== pipelined upper-triangle items ==============
    const int item0 = (bid - NPOSB) * TPB;
    int ti, tj;
    trimap(item0, ti, tj);
    int row0 = ti * 128, col0 = tj * 128;
    bool diag = (ti == tj);

    bf16x8 afA[2][4], afB[2][4];
    LOADA(afA, row0);
    STAGEB(0, col0, 0);                  // item0 h0 -> buf0

    float sn[8], colp[8];
    #pragma unroll
    for (int q = 0; q < 8; ++q) { sn[q] = 0.f; colp[q] = 0.f; }

    __syncthreads();                     // buf0 landed
    STAGEB(16384, col0, 1);              // item0 h1 -> buf1 (flies during h0)

    #pragma unroll
    for (int i = 0; i < TPB; ++i) {
      int nti = 0, ntj = 0, nrow0 = 0, ncol0 = 0;
      bool ndiag = false;

      // phase (i, h0) from buf0
      if ((i & 1) == 0) { COMPUTE_HALF(afA, 0, 0, row0, diag); }
      else              { COMPUTE_HALF(afB, 0, 0, row0, diag); }
      __syncthreads();                   // (i,h1) staging landed in buf1
      if (i < TPB - 1) {                 // prefetch next item: B h0 + A frags
        trimap(item0 + i + 1, nti, ntj);
        nrow0 = nti * 128; ncol0 = ntj * 128; ndiag = (nti == ntj);
        STAGEB(0, ncol0, 0);             // hides behind (i,h1) compute
        if ((i & 1) == 0) { LOADA(afB, nrow0); }
        else              { LOADA(afA, nrow0); }
      }

      // phase (i, h1) from buf1
      if ((i & 1) == 0) { COMPUTE_HALF(afA, 16384, 1, row0, diag); }
      else              { COMPUTE_HALF(afB, 16384, 1, row0, diag); }

      // finish item i: row sums + colp reduce + colbuf publish
      #pragma unroll
      for (int q = 0; q < 8; ++q) {
        #pragma unroll
        for (int off = 1; off < 16; off <<= 1) sn[q] += __shfl_xor(sn[q], off);
      }
      if (lr_ == 0) {
        #pragma unroll
        for (int m = 0; m < 2; ++m)
          #pragma unroll
          for (int j = 0; j < 4; ++j) {
            const int row = row0 + w * 32 + m * 16 + lg * 4 + j;
            part[(size_t)tj * NB + row] = sn[m * 4 + j];
          }
      }
      #pragma unroll
      for (int q = 0; q < 8; ++q) {
        colp[q] += __shfl_xor(colp[q], 16);
        colp[q] += __shfl_xor(colp[q], 32);
      }
      if (!diag && l < 16) {
        #pragma unroll
        for (int q = 0; q < 8; ++q)
          colbuf[w * 128 + (q >> 2) * 64 + (q & 3) * 16 + lr_] = colp[q];
      }

      __syncthreads();                   // (i+1,h0) staging landed; colbuf ready
      if (i < TPB - 1) STAGEB(16384, ncol0, 1);   // hides behind (i+1,h0)
      if (!diag && tid < 128) {
        const float cs_ = colbuf[tid] + colbuf[128 + tid] +
                          colbuf[256 + tid] + colbuf[384 + tid];
        part[(size_t)ti * NB + col0 + tid] = cs_;
      }
      // rotate to next item
      #pragma unroll
      for (int q = 0; q < 8; ++q) { sn[q] = 0.f; colp[q] = 0.f; }
      ti = nti; tj = ntj; row0 = nrow0; col0 = ncol0; diag = ndiag;
    }
  } else {
    // ================= per-label positives + same-label correction =========
    int* lab = (int*)S;                        // 8192 ints = 32 KB
    for (int i = tid; i < NB / 4; i += 256)
      ((int4*)lab)[i] = ((const int4*)labels)[i];
    __syncthreads();

    const int L = bid * 4 + w;                 // one wave per label
    int* memL = (int*)(S + 32768) + w * MAXM;

    // build ordered member list via ballot rounds (ascending index order)
    int cnt = 0;
    for (int base = 0; base < NB; base += 64) {
      const int lv = lab[base + l];
      const unsigned long long mk = __ballot(lv == L);
      if (lv == L) {
        const int pos = __popcll(mk & ((1ull << l) - 1));
        if (cnt + pos < MAXM) memL[cnt + pos] = base + l;
      }
      cnt += __popcll(mk);
    }
    int c = cnt > MAXM ? MAXM : cnt;
    __syncthreads();   // memL visible across lanes of each wave

    const int nt = (c + 15) >> 4;
    for (int rb = 0; rb < nt; ++rb) {
      const int ri = rb * 16 + lr_;
      bf16x8 af[4];
      if (ri < c) {
        const u16* src = e + (size_t)memL[ri] * ND;
        #pragma unroll
        for (int ks = 0; ks < 4; ++ks)
          af[ks] = *(const bf16x8*)(src + ks * 32 + lg * 8);
      } else {
        #pragma unroll
        for (int ks = 0; ks < 4; ++ks) af[ks] = (bf16x8)0;
      }
      float corr[4], mp[4], sp[4];
      #pragma unroll
      for (int r = 0; r < 4; ++r) { corr[r] = 0.f; mp[r] = SENT; sp[r] = 0.f; }

      for (int cb = 0; cb < nt; ++cb) {
        const int ci = cb * 16 + lr_;
        bf16x8 bfr[4];
        if (ci < c) {
          const u16* src = e + (size_t)memL[ci] * ND;
          #pragma unroll
          for (int ks = 0; ks < 4; ++ks)
            bfr[ks] = *(const bf16x8*)(src + ks * 32 + lg * 8);
        } else {
          #pragma unroll
          for (int ks = 0; ks < 4; ++ks) bfr[ks] = (bf16x8)0;
        }
        f32x4 acc;
        #pragma unroll
        for (int r = 0; r < 4; ++r) acc[r] = 0.f;
        #pragma unroll
        for (int ks = 0; ks < 4; ++ks)
          acc = __builtin_amdgcn_mfma_f32_16x16x32_bf16(af[ks], bfr[ks], acc, 0, 0, 0);

        #pragma unroll
        for (int r = 0; r < 4; ++r) {
          const int R = rb * 16 + lg * 4 + r;
          const int Cj = cb * 16 + lr_;
          const bool ok = (R < c) && (Cj < c) && (R != Cj);
          const float sv = acc[r];
          float xn = fmaf(sv * sv, G2, NEG_C);
          xn = (sv > -0.25f) ? xn : 0.f;
          corr[r] += ok ? fexp2(xn) : 0.f;
          if (ok) {
            const float t1 = 1.25f - sv;
            const float xp = G2 * fmaxf(t1, 0.f) * (t1 - 0.5f);
            if (xp > mp[r]) { sp[r] = sp[r] * fexp2(mp[r] - xp) + 1.f; mp[r] = xp; }
            else sp[r] += fexp2(xp - mp[r]);
          }
        }
      }
      #pragma unroll
      for (int r = 0; r < 4; ++r) {
        #pragma unroll
        for (int off = 1; off < 16; off <<= 1) {
          corr[r] += __shfl_xor(corr[r], off);
          const float m2 = __shfl_xor(mp[r], off), s2 = __shfl_xor(sp[r], off);
          const float M = fmaxf(mp[r], m2);
          const float t1 = sp[r] * fexp2(mp[r] - M);  // exp2(-1e30)=0 for empties
          const float t2 = s2 * fexp2(m2 - M);
          mp[r] = M; sp[r] = t1 + t2;
        }
      }
      if (lr_ == 0) {
        #pragma unroll
        for (int r = 0; r < 4; ++r) {
          const int R = rb * 16 + lg * 4 + r;
          if (R < c) {
            float* o = poscorr + (size_t)memL[R] * 4;
            o[0] = mp[r]; o[1] = sp[r]; o[2] = corr[r]; o[3] = (float)(c - 1);
          }
        }
      }
    }
  }
}

// ---- k3: per-row finish (64 blocks x 128 rows) + fused final scalar -------
__global__ __launch_bounds__(128) void k_rowsfinal(const float* __restrict__ part,
                                                   const float* __restrict__ poscorr,
                                                   float* __restrict__ bsum,
                                                   int* __restrict__ counter,
                                                   float* __restrict__ out) {
  const int bid = blockIdx.x;
  const int tid = threadIdx.x;
  const int l = tid & 63, w = tid >> 6;
  const int row = bid * 128 + tid;
  float sn = 0.f;
  #pragma unroll 8
  for (int q = 0; q < NT; ++q)
    sn += part[(size_t)q * NB + row];    // coalesced: 128 consecutive floats/q
  const float4 pc = *reinterpret_cast<const float4*>(poscorr + (size_t)row * 4);
  const int npi = (int)(pc.w + 0.5f);
  const bool valid = (npi > 0) && (npi < NB - 1);
  float val = 0.f;
  if (valid) {
    const float snn = fmaxf(sn - pc.z, 1e-30f);
    const float lp = LN2F * (pc.x + log2f(pc.y));
    const float ln_ = LN2F * log2f(snn);
    const float x = lp + ln_;
    val = fmaxf(x, 0.f) + log1pf(expf(-fabsf(x)));  // stable softplus
  }
  float cnt = valid ? 1.f : 0.f;
  val = wave_sum_f(val);
  cnt = wave_sum_f(cnt);
  __shared__ float svals[2], scnts[2];
  __shared__ int lastflag;
  if (l == 0) { svals[w] = val; scnts[w] = cnt; }
  __syncthreads();
  if (tid == 0) {
    bsum[bid * 2 + 0] = svals[0] + svals[1];
    bsum[bid * 2 + 1] = scnts[0] + scnts[1];
    __threadfence();                       // publish bsum device-wide
    const int prev = atomicAdd(counter, 1);
    lastflag = (prev == NRF - 1);
  }
  __syncthreads();
  if (lastflag && w == 0) {
    __threadfence();                       // acquire all blocks' bsum
    volatile const float* vb = (volatile const float*)bsum;
    float s = vb[l * 2];                   // 64 lanes <-> 64 blocks exactly
    float c = vb[l * 2 + 1];
    s = wave_sum_f(s);
    c = wave_sum_f(c);
    if (l == 0) out[0] = s / fmaxf(c, 1.f);
  }
}

extern "C" void kernel_launch(void* const* d_in, const int* in_sizes, int n_in,
                              void* d_out, int out_size, void* d_ws, size_t ws_size,
                              hipStream_t stream) {
  const float* emb = (const float*)d_in[0];
  const int* labels = (const int*)d_in[1];
  float* out = (float*)d_out;
  char* ws = (char*)d_ws;

  float* part    = (float*)(ws + 0);         // 64*8192*4  = 2097152
  float* poscorr = (float*)(ws + 2097152);   // 8192*4*4   = 131072
  u16*   ebf     = (u16*)  (ws + 2228224);   // 8192*128*2 = 2097152
  float* bsum    = (float*)(ws + 4325376);   // 512 B
  int*   counter = (int*)  (ws + 4325888);   // 8 B

  k_prep<<<NB / 8, 512, 0, stream>>>(emb, ebf, counter);
  k_mainpos<<<NPOSB + NTRB, 256, 0, stream>>>(ebf, labels, part, poscorr);
  k_rowsfinal<<<NRF, 128, 0, stream>>>(part, poscorr, bsum, counter, out);
}

// Round 18
// 41.535 us; speedup vs baseline: 1.0102x; 1.0102x over previous
//
#include <hip/hip_runtime.h>
#include <math.h>

#define NB 8192
#define ND 128
#define NT 64        // number of 128-row tiles
#define NTRI 2080    // NT*(NT+1)/2 upper-triangle tile pairs
#define TPB 4        // tile-pairs per block (pipelined)
#define NTRB (NTRI / TPB)   // 520 triangle blocks
#define NPOSB 128    // per-label blocks (dispatch FIRST: bids 0..127)
#define NLAB 512
#define MAXM 64
#define NRF 64       // k_rowsfinal blocks (128 rows each)

typedef unsigned short u16;
typedef unsigned int u32;
typedef __attribute__((ext_vector_type(8))) short bf16x8;
typedef __attribute__((ext_vector_type(4))) float f32x4;

#define G2 369.3299304675746f         // gamma * log2(e)
#define NEG_C (-23.083120654223414f)  // -G2/16
#define SENT (-1e30f)
#define LN2F 0.6931471805599453f

static __device__ __forceinline__ void gload16(const void* g, void* l) {
  __builtin_amdgcn_global_load_lds(
      (const __attribute__((address_space(1))) u32*)g,
      (__attribute__((address_space(3))) u32*)l, 16, 0, 0);
}

static __device__ __forceinline__ float fexp2(float x) {
  return __builtin_amdgcn_exp2f(x);
}

static __device__ __forceinline__ u16 f2bf(float f) {
  u32 u = __float_as_uint(f);
  u32 r = (u + 0x7FFF + ((u >> 16) & 1)) >> 16;   // RNE
  return (u16)r;
}

static __device__ __forceinline__ float wave_sum_f(float v) {
  #pragma unroll
  for (int off = 1; off < 64; off <<= 1) v += __shfl_xor(v, off);
  return v;
}

static __device__ __forceinline__ int pre_(int t) { return t * NT - (t * (t - 1)) / 2; }
static __device__ __forceinline__ void trimap(int item, int& ti, int& tj) {
  int t = (int)((129.0f - sqrtf(16641.0f - 8.0f * (float)item)) * 0.5f);
  if (t > NT - 1) t = NT - 1;
  if (t < 0) t = 0;
  while (pre_(t + 1) <= item) ++t;
  while (pre_(t) > item) --t;
  ti = t;
  tj = t + (item - pre_(t));
}

// ---- k1: normalize rows + cast to bf16; reset arrival counter -------------
__global__ __launch_bounds__(512) void k_prep(const float* __restrict__ emb,
                                              u16* __restrict__ e,
                                              int* __restrict__ counters) {
  if (blockIdx.x == 0 && threadIdx.x < 2) counters[threadIdx.x] = 0;
  const int l = threadIdx.x & 63;
  const int w = threadIdx.x >> 6;
  const int row = blockIdx.x * 8 + w;
  const float2 v = reinterpret_cast<const float2*>(emb)[(size_t)row * 64 + l];
  float ss = wave_sum_f(v.x * v.x + v.y * v.y);
  const float inv = 1.0f / fmaxf(sqrtf(ss), 1e-12f);
  ushort2 o;
  o.x = f2bf(v.x * inv);
  o.y = f2bf(v.y * inv);
  reinterpret_cast<ushort2*>(e)[(size_t)row * 64 + l] = o;
}

// staging / A-load / compute as macros -> all register indices compile-time
#define LOADA(AF, ROW0)                                                         \
  _Pragma("unroll")                                                             \
  for (int m_ = 0; m_ < 2; ++m_) {                                              \
    _Pragma("unroll")                                                           \
    for (int ks_ = 0; ks_ < 4; ++ks_)                                           \
      AF[m_][ks_] = *(const bf16x8*)(e + (size_t)((ROW0) + w * 32 + m_ * 16 + lr_) * ND + ks_ * 32 + lg * 8); \
  }

#define STAGEB(BUFOFF, COL0, H)                                                 \
  _Pragma("unroll")                                                             \
  for (int i_ = 0; i_ < 4; ++i_) {                                              \
    const int rr_ = w * 16 + i_ * 4 + lg;                                       \
    gload16(e + (size_t)((COL0) + (H) * 64 + rr_) * ND + (lr_ ^ (rr_ & 15)) * 8, \
            S + (BUFOFF) + w * 4096 + i_ * 1024);                               \
  }

#define COMPUTE_HALF(AF, BUFOFF, H, ROW0, DIAG)                                 \
  {                                                                             \
    f32x4 acc[2][4];                                                            \
    _Pragma("unroll") for (int m_ = 0; m_ < 2; ++m_)                            \
      _Pragma("unroll") for (int n_ = 0; n_ < 4; ++n_)                          \
        _Pragma("unroll") for (int q_ = 0; q_ < 4; ++q_) acc[m_][n_][q_] = 0.f; \
    _Pragma("unroll") for (int ks_ = 0; ks_ < 4; ++ks_) {                       \
      const int kslot_ = (ks_ * 4 + lg) ^ lr_;                                  \
      bf16x8 bfr[4];                                                            \
      _Pragma("unroll") for (int n_ = 0; n_ < 4; ++n_)                          \
        bfr[n_] = *(const bf16x8*)(S + (BUFOFF) + (n_ * 16 + lr_) * 256 + kslot_ * 16); \
      _Pragma("unroll") for (int m_ = 0; m_ < 2; ++m_)                          \
        _Pragma("unroll") for (int n_ = 0; n_ < 4; ++n_)                        \
          acc[m_][n_] = __builtin_amdgcn_mfma_f32_16x16x32_bf16(AF[m_][ks_], bfr[n_], acc[m_][n_], 0, 0, 0); \
    }                                                                           \
    _Pragma("unroll") for (int m_ = 0; m_ < 2; ++m_) {                          \
      _Pragma("unroll") for (int n_ = 0; n_ < 4; ++n_) {                        \
        const bool dmn_ = (DIAG) && (w * 32 + m_ * 16 == (H) * 64 + n_ * 16);   \
        float scc_ = 0.f;                                                       \
        _Pragma("unroll") for (int j_ = 0; j_ < 4; ++j_) {                      \
          const float sv_ = acc[m_][n_][j_];                                    \
          float xn_ = fmaf(sv_ * sv_, G2, NEG_C);                               \
          xn_ = (sv_ > -0.25f) ? xn_ : 0.f;                                     \
          if (dmn_) xn_ = (lr_ == lg * 4 + j_) ? SENT : xn_;                    \
          const float ev_ = fexp2(xn_);                                         \
          sn[m_ * 4 + j_] += ev_;                                               \
          scc_ += ev_;                                                          \
        }                                                                       \
        colp[(H) * 4 + n_] += scc_;                                             \
      }                                                                         \
    }                                                                           \
  }

// ---- k2: pos blocks FIRST (bids 0..127) | pipelined triangle tiles --------
// (256,3): 3 blocks/CU -> all 648 blocks co-resident (one dispatch wave-front,
// imbalance absorbed by concurrency). VGPR cap 170; rounds 5-15 compiled this
// code shape at 68-128 VGPR, so no spill expected.
__global__ __launch_bounds__(256, 3) void k_mainpos(const u16* __restrict__ e,
                                                    const int* __restrict__ labels,
                                                    float* __restrict__ part,
                                                    float* __restrict__ poscorr) {
  __shared__ __align__(16) char S[34816];   // buf0(16K) buf1(16K) colbuf(2K)
  float* colbuf = (float*)(S + 32768);
  const int bid = blockIdx.x;
  const int tid = threadIdx.x;
  const int l = tid & 63;
  const int w = tid >> 6;
  const int lr_ = l & 15;
  const int lg = l >> 4;

  if (bid >= NPOSB) {
    // ============== pipelined upper-triangle items ==============
    const int item0 = (bid - NPOSB) * TPB;
    int ti, tj;
    trimap(item0, ti, tj);
    int row0 = ti * 128, col0 = tj * 128;
    bool diag = (ti == tj);

    bf16x8 afA[2][4], afB[2][4];
    LOADA(afA, row0);
    STAGEB(0, col0, 0);                  // item0 h0 -> buf0

    float sn[8], colp[8];
    #pragma unroll
    for (int q = 0; q < 8; ++q) { sn[q] = 0.f; colp[q] = 0.f; }

    __syncthreads();                     // buf0 landed
    STAGEB(16384, col0, 1);              // item0 h1 -> buf1 (flies during h0)

    #pragma unroll
    for (int i = 0; i < TPB; ++i) {
      int nti = 0, ntj = 0, nrow0 = 0, ncol0 = 0;
      bool ndiag = false;

      // phase (i, h0) from buf0
      if ((i & 1) == 0) { COMPUTE_HALF(afA, 0, 0, row0, diag); }
      else              { COMPUTE_HALF(afB, 0, 0, row0, diag); }
      __syncthreads();                   // (i,h1) staging landed in buf1
      if (i < TPB - 1) {                 // prefetch next item: B h0 + A frags
        trimap(item0 + i + 1, nti, ntj);
        nrow0 = nti * 128; ncol0 = ntj * 128; ndiag = (nti == ntj);
        STAGEB(0, ncol0, 0);             // hides behind (i,h1) compute
        if ((i & 1) == 0) { LOADA(afB, nrow0); }
        else              { LOADA(afA, nrow0); }
      }

      // phase (i, h1) from buf1
      if ((i & 1) == 0) { COMPUTE_HALF(afA, 16384, 1, row0, diag); }
      else              { COMPUTE_HALF(afB, 16384, 1, row0, diag); }

      // finish item i: row sums + colp reduce + colbuf publish
      #pragma unroll
      for (int q = 0; q < 8; ++q) {
        #pragma unroll
        for (int off = 1; off < 16; off <<= 1) sn[q] += __shfl_xor(sn[q], off);
      }
      if (lr_ == 0) {
        #pragma unroll
        for (int m = 0; m < 2; ++m)
          #pragma unroll
          for (int j = 0; j < 4; ++j) {
            const int row = row0 + w * 32 + m * 16 + lg * 4 + j;
            part[(size_t)tj * NB + row] = sn[m * 4 + j];
          }
      }
      #pragma unroll
      for (int q = 0; q < 8; ++q) {
        colp[q] += __shfl_xor(colp[q], 16);
        colp[q] += __shfl_xor(colp[q], 32);
      }
      if (!diag && l < 16) {
        #pragma unroll
        for (int q = 0; q < 8; ++q)
          colbuf[w * 128 + (q >> 2) * 64 + (q & 3) * 16 + lr_] = colp[q];
      }

      __syncthreads();                   // (i+1,h0) staging landed; colbuf ready
      if (i < TPB - 1) STAGEB(16384, ncol0, 1);   // hides behind (i+1,h0)
      if (!diag && tid < 128) {
        const float cs_ = colbuf[tid] + colbuf[128 + tid] +
                          colbuf[256 + tid] + colbuf[384 + tid];
        part[(size_t)ti * NB + col0 + tid] = cs_;
      }
      // rotate to next item
      #pragma unroll
      for (int q = 0; q < 8; ++q) { sn[q] = 0.f; colp[q] = 0.f; }
      ti = nti; tj = ntj; row0 = nrow0; col0 = ncol0; diag = ndiag;
    }
  } else {
    // ================= per-label positives + same-label correction =========
    int* lab = (int*)S;                        // 8192 ints = 32 KB
    for (int i = tid; i < NB / 4; i += 256)
      ((int4*)lab)[i] = ((const int4*)labels)[i];
    __syncthreads();

    const int L = bid * 4 + w;                 // one wave per label
    int* memL = (int*)(S + 32768) + w * MAXM;

    // build ordered member list via ballot rounds (ascending index order)
    int cnt = 0;
    for (int base = 0; base < NB; base += 64) {
      const int lv = lab[base + l];
      const unsigned long long mk = __ballot(lv == L);
      if (lv == L) {
        const int pos = __popcll(mk & ((1ull << l) - 1));
        if (cnt + pos < MAXM) memL[cnt + pos] = base + l;
      }
      cnt += __popcll(mk);
    }
    int c = cnt > MAXM ? MAXM : cnt;
    __syncthreads();   // memL visible across lanes of each wave

    const int nt = (c + 15) >> 4;
    for (int rb = 0; rb < nt; ++rb) {
      const int ri = rb * 16 + lr_;
      bf16x8 af[4];
      if (ri < c) {
        const u16* src = e + (size_t)memL[ri] * ND;
        #pragma unroll
        for (int ks = 0; ks < 4; ++ks)
          af[ks] = *(const bf16x8*)(src + ks * 32 + lg * 8);
      } else {
        #pragma unroll
        for (int ks = 0; ks < 4; ++ks) af[ks] = (bf16x8)0;
      }
      float corr[4], mp[4], sp[4];
      #pragma unroll
      for (int r = 0; r < 4; ++r) { corr[r] = 0.f; mp[r] = SENT; sp[r] = 0.f; }

      for (int cb = 0; cb < nt; ++cb) {
        const int ci = cb * 16 + lr_;
        bf16x8 bfr[4];
        if (ci < c) {
          const u16* src = e + (size_t)memL[ci] * ND;
          #pragma unroll
          for (int ks = 0; ks < 4; ++ks)
            bfr[ks] = *(const bf16x8*)(src + ks * 32 + lg * 8);
        } else {
          #pragma unroll
          for (int ks = 0; ks < 4; ++ks) bfr[ks] = (bf16x8)0;
        }
        f32x4 acc;
        #pragma unroll
        for (int r = 0; r < 4; ++r) acc[r] = 0.f;
        #pragma unroll
        for (int ks = 0; ks < 4; ++ks)
          acc = __builtin_amdgcn_mfma_f32_16x16x32_bf16(af[ks], bfr[ks], acc, 0, 0, 0);

        #pragma unroll
        for (int r = 0; r < 4; ++r) {
          const int R = rb * 16 + lg * 4 + r;
          const int Cj = cb * 16 + lr_;
          const bool ok = (R < c) && (Cj < c) && (R != Cj);
          const float sv = acc[r];
          float xn = fmaf(sv * sv, G2, NEG_C);
          xn = (sv > -0.25f) ? xn : 0.f;
          corr[r] += ok ? fexp2(xn) : 0.f;
          if (ok) {
            const float t1 = 1.25f - sv;
            const float xp = G2 * fmaxf(t1, 0.f) * (t1 - 0.5f);
            if (xp > mp[r]) { sp[r] = sp[r] * fexp2(mp[r] - xp) + 1.f; mp[r] = xp; }
            else sp[r] += fexp2(xp - mp[r]);
          }
        }
      }
      #pragma unroll
      for (int r = 0; r < 4; ++r) {
        #pragma unroll
        for (int off = 1; off < 16; off <<= 1) {
          corr[r] += __shfl_xor(corr[r], off);
          const float m2 = __shfl_xor(mp[r], off), s2 = __shfl_xor(sp[r], off);
          const float M = fmaxf(mp[r], m2);
          const float t1 = sp[r] * fexp2(mp[r] - M);  // exp2(-1e30)=0 for empties
          const float t2 = s2 * fexp2(m2 - M);
          mp[r] = M; sp[r] = t1 + t2;
        }
      }
      if (lr_ == 0) {
        #pragma unroll
        for (int r = 0; r < 4; ++r) {
          const int R = rb * 16 + lg * 4 + r;
          if (R < c) {
            float* o = poscorr + (size_t)memL[R] * 4;
            o[0] = mp[r]; o[1] = sp[r]; o[2] = corr[r]; o[3] = (float)(c - 1);
          }
        }
      }
    }
  }
}

// ---- k3: per-row finish (64 blocks x 128 rows) + fused final scalar -------
__global__ __launch_bounds__(128) void k_rowsfinal(const float* __restrict__ part,
                                                   const float* __restrict__ poscorr,
                                                   float* __restrict__ bsum,
                                                   int* __restrict__ counter,
                                                   float* __restrict__ out) {
  const int bid = blockIdx.x;
  const int tid = threadIdx.x;
  const int l = tid & 63, w = tid >> 6;
  const int row = bid * 128 + tid;
  float sn = 0.f;
  #pragma unroll 8
  for (int q = 0; q < NT; ++q)
    sn += part[(size_t)q * NB + row];    // coalesced: 128 consecutive floats/q
  const float4 pc = *reinterpret_cast<const float4*>(poscorr + (size_t)row * 4);
  const int npi = (int)(pc.w + 0.5f);
  const bool valid = (npi > 0) && (npi < NB - 1);
  float val = 0.f;
  if (valid) {
    const float snn = fmaxf(sn - pc.z, 1e-30f);
    const float lp = LN2F * (pc.x + log2f(pc.y));
    const float ln_ = LN2F * log2f(snn);
    const float x = lp + ln_;
    val = fmaxf(x, 0.f) + log1pf(expf(-fabsf(x)));  // stable softplus
  }
  float cnt = valid ? 1.f : 0.f;
  val = wave_sum_f(val);
  cnt = wave_sum_f(cnt);
  __shared__ float svals[2], scnts[2];
  __shared__ int lastflag;
  if (l == 0) { svals[w] = val; scnts[w] = cnt; }
  __syncthreads();
  if (tid == 0) {
    bsum[bid * 2 + 0] = svals[0] + svals[1];
    bsum[bid * 2 + 1] = scnts[0] + scnts[1];
    __threadfence();                       // publish bsum device-wide
    const int prev = atomicAdd(counter, 1);
    lastflag = (prev == NRF - 1);
  }
  __syncthreads();
  if (lastflag && w == 0) {
    __threadfence();                       // acquire all blocks' bsum
    volatile const float* vb = (volatile const float*)bsum;
    float s = vb[l * 2];                   // 64 lanes <-> 64 blocks exactly
    float c = vb[l * 2 + 1];
    s = wave_sum_f(s);
    c = wave_sum_f(c);
    if (l == 0) out[0] = s / fmaxf(c, 1.f);
  }
}

extern "C" void kernel_launch(void* const* d_in, const int* in_sizes, int n_in,
                              void* d_out, int out_size, void* d_ws, size_t ws_size,
                              hipStream_t stream) {
  const float* emb = (const float*)d_in[0];
  const int* labels = (const int*)d_in[1];
  float* out = (float*)d_out;
  char* ws = (char*)d_ws;

  float* part    = (float*)(ws + 0);         // 64*8192*4  = 2097152
  float* poscorr = (float*)(ws + 2097152);   // 8192*4*4   = 131072
  u16*   ebf     = (u16*)  (ws + 2228224);   // 8192*128*2 = 2097152
  float* bsum    = (float*)(ws + 4325376);   // 512 B
  int*   counter = (int*)  (ws + 4325888);   // 8 B

  k_prep<<<NB / 8, 512, 0, stream>>>(emb, ebf, counter);
  k_mainpos<<<NPOSB + NTRB, 256, 0, stream>>>(ebf, labels, part, poscorr);
  k_rowsfinal<<<NRF, 128, 0, stream>>>(part, poscorr, bsum, counter, out);
}